// Round 13
// baseline (115.702 us; speedup 1.0000x reference)
//
#include <hip/hip_runtime.h>
#include <hip/hip_bf16.h>

static constexpr int Bn = 2, Tn = 2048, Cn = 1024, Hn = 16, HSn = 64;
static constexpr int Mrows = Bn * Tn;                 // 4096
static constexpr size_t PL = (size_t)Bn * Hn * Tn * HSn;  // one qkv plane (4.19M)

typedef __attribute__((ext_vector_type(8))) short short8;
typedef __attribute__((ext_vector_type(4))) float f32x4;

__device__ __forceinline__ unsigned short f2bf(float f) {
  __hip_bfloat16 h = __float2bfloat16(f);
  return *reinterpret_cast<unsigned short*>(&h);
}

__device__ __forceinline__ float fexp2(float x) {
  return __builtin_amdgcn_exp2f(x);
}

__device__ __forceinline__ void gload_lds16(const void* g, void* l) {
  __builtin_amdgcn_global_load_lds(
      (const __attribute__((address_space(1))) void*)g,
      (__attribute__((address_space(3))) void*)l, 16, 0, 0);
}

// qscale folded into Q plane at GEMM epilogue: (1/sqrt(64)) * log2(e)
#define QSC 0.18033688011112042591999058512524f

// ---------------------------------------------------------------------------
// merged prep kernel (unchanged)
// ---------------------------------------------------------------------------
__global__ __launch_bounds__(256) void prep_all(
    const float* __restrict__ x, unsigned short* __restrict__ xb,
    const float* __restrict__ Wa, unsigned short* __restrict__ Wab,
    const float* __restrict__ Wp, unsigned short* __restrict__ Wpb)
{
  const int bid = blockIdx.x, tid = threadIdx.x;
  if (bid < 4096) {
    int i = bid * 256 + tid;
    float4 v = ((const float4*)x)[i];
    ushort4 o;
    o.x = f2bf(v.x); o.y = f2bf(v.y); o.z = f2bf(v.z); o.w = f2bf(v.w);
    ((ushort4*)xb)[i] = o;
    return;
  }
  __shared__ float tile[32][33];
  const float* src; unsigned short* dst; int R, Cc, tb;
  if (bid < 4096 + 3072) { src = Wa; dst = Wab; R = Cn; Cc = 3 * Cn; tb = bid - 4096; }
  else                   { src = Wp; dst = Wpb; R = Cn; Cc = Cn;     tb = bid - 4096 - 3072; }
  const int nbx = Cc / 32;
  const int bx = tb % nbx, by = tb / nbx;
  const int tx = tid & 31, ty = tid >> 5;
  const int c0 = bx * 32, r0 = by * 32;
  #pragma unroll
  for (int i = 0; i < 4; ++i)
    tile[ty + 8 * i][tx] = src[(size_t)(r0 + ty + 8 * i) * Cc + c0 + tx];
  __syncthreads();
  #pragma unroll
  for (int i = 0; i < 4; ++i)
    dst[(size_t)(c0 + ty + 8 * i) * R + r0 + tx] = f2bf(tile[tx][ty + 8 * i]);
}

// ---------------------------------------------------------------------------
// QKV GEMM, 256x192 tile, grid 256 (1/CU), XCD swizzle (unchanged from R11)
// ---------------------------------------------------------------------------
__global__ __launch_bounds__(512) void gemmQKV(
    const unsigned short* __restrict__ A, const unsigned short* __restrict__ Bt,
    const float* __restrict__ bias, unsigned short* __restrict__ qkv, int K)
{
  constexpr int NSTEP = 1024 / 64;     // 16 K-steps
  constexpr int AF = 32;               // 16 mg x 2 ks
  constexpr int BF = 24;               // 12 ng x 2 ks
  __shared__ alignas(16) unsigned char lds[2][(AF + BF) * 1024];

  const int tid = threadIdx.x, wave = tid >> 6, lane = tid & 63;
  const int wr = wave >> 2, wc = wave & 3;            // 2 x 4 wave grid
  const int orig = blockIdx.x;
  const int swz = (orig & 7) * 32 + (orig >> 3);
  const int bx = swz & 15, by = swz >> 4;
  const int tM = by * 256, tN = bx * 192;

  auto STAGE = [&](int buf, int k0) {
    #pragma unroll
    for (int i = 0; i < 7; ++i) {
      int f = wave * 7 + i;
      const unsigned short* g;
      int off;
      if (f < AF) {
        int mg = f >> 1, ks = f & 1;
        g = A + (size_t)(tM + mg * 16 + (lane & 15)) * K + k0 + ks * 32 + (lane >> 4) * 8;
        off = f * 1024;
      } else {
        int fg = f - AF;
        int ng = fg >> 1, ks = fg & 1;
        g = Bt + (size_t)(tN + ng * 16 + (lane & 15)) * K + k0 + ks * 32 + (lane >> 4) * 8;
        off = AF * 1024 + fg * 1024;
      }
      gload_lds16(g, &lds[buf][off]);
    }
  };

  f32x4 acc[8][3] = {};

  STAGE(0, 0);
  STAGE(1, 64);

  for (int t = 0; t < NSTEP; ++t) {
    if (t == NSTEP - 1)
      asm volatile("s_waitcnt vmcnt(0)" ::: "memory");
    else
      asm volatile("s_waitcnt vmcnt(7)" ::: "memory");
    __builtin_amdgcn_s_barrier();

    const int cur = t & 1;
    short8 af[8][2], bfr[3][2];
    #pragma unroll
    for (int ks = 0; ks < 2; ++ks) {
      #pragma unroll
      for (int m = 0; m < 8; ++m)
        af[m][ks] = *(const short8*)&lds[cur][((wr * 8 + m) * 2 + ks) * 1024 + lane * 16];
      #pragma unroll
      for (int n = 0; n < 3; ++n)
        bfr[n][ks] = *(const short8*)&lds[cur][AF * 1024 + ((wc * 3 + n) * 2 + ks) * 1024 + lane * 16];
    }
    asm volatile("s_waitcnt lgkmcnt(0)" ::: "memory");
    __builtin_amdgcn_sched_barrier(0);
    __builtin_amdgcn_s_barrier();

    if (t + 2 < NSTEP) STAGE(cur, (t + 2) * 64);

    __builtin_amdgcn_s_setprio(1);
    #pragma unroll
    for (int ks = 0; ks < 2; ++ks)
      #pragma unroll
      for (int m = 0; m < 8; ++m)
        #pragma unroll
        for (int n = 0; n < 3; ++n)
          acc[m][n] = __builtin_amdgcn_mfma_f32_16x16x32_bf16(af[m][ks], bfr[n][ks], acc[m][n], 0, 0, 0);
    __builtin_amdgcn_s_setprio(0);
  }

  const int a = lane & 15, hq = lane >> 4;
  #pragma unroll
  for (int m = 0; m < 8; ++m) {
    #pragma unroll
    for (int n = 0; n < 3; ++n) {
      int c = tN + wc * 48 + n * 16 + a;
      float bv = bias[c];
      int which = c >> 10;
      int cc = c & 1023, hh = cc >> 6, d = cc & 63;
      int row0 = tM + wr * 128 + m * 16 + hq * 4;
      int b = row0 >> 11, t0 = row0 & 2047;
      int bh = b * Hn + hh;
      if (which == 2) {
        ushort4 pk;
        pk.x = f2bf(acc[m][n][0] + bv);
        pk.y = f2bf(acc[m][n][1] + bv);
        pk.z = f2bf(acc[m][n][2] + bv);
        pk.w = f2bf(acc[m][n][3] + bv);
        *(ushort4*)&qkv[2 * PL + ((size_t)bh * HSn + d) * Tn + t0] = pk;
      } else {
        float sc = (which == 0) ? QSC : 1.0f;
        #pragma unroll
        for (int r = 0; r < 4; ++r) {
          float v = (acc[m][n][r] + bv) * sc;
          qkv[(size_t)which * PL + ((size_t)bh * Tn + t0 + r) * HSn + d] = f2bf(v);
        }
      }
    }
  }
}

// ---------------------------------------------------------------------------
// proj GEMM (unchanged R7 structure)
// ---------------------------------------------------------------------------
template <int WM, int WN>
__global__ __launch_bounds__(256) void gemmP(
    const unsigned short* __restrict__ A, const unsigned short* __restrict__ Bt,
    const float* __restrict__ bias, float* __restrict__ O, int N, int K)
{
  constexpr int BM = WM * 32, BNt = WN * 32;
  constexpr int AF = BM / 16;
  constexpr int BF = BNt / 16;
  constexpr int NF = AF + BF;
  constexpr int PW = NF / 4;
  static_assert(PW == 3, "vmcnt literal");
  __shared__ alignas(16) unsigned char lds[2][NF * 1024];

  const int tid = threadIdx.x, wave = tid >> 6, lane = tid & 63;
  const int wr = wave >> 1, wc = wave & 1;
  const int tM = blockIdx.y * BM, tN = blockIdx.x * BNt;

  auto STAGE = [&](int buf, int k0) {
    #pragma unroll
    for (int i = 0; i < PW; ++i) {
      int f = wave * PW + i;
      const unsigned short* g;
      if (f < AF)
        g = A + (size_t)(tM + f * 16 + (lane & 15)) * K + k0 + (lane >> 4) * 8;
      else
        g = Bt + (size_t)(tN + (f - AF) * 16 + (lane & 15)) * K + k0 + (lane >> 4) * 8;
      gload_lds16(g, &lds[buf][f * 1024]);
    }
  };

  f32x4 acc[WM][WN] = {};

  STAGE(0, 0);
  for (int t = 0, k0 = 0;; ++t, k0 += 32) {
    const int cur = t & 1;
    if (k0 + 32 < K) {
      STAGE(cur ^ 1, k0 + 32);
      asm volatile("s_waitcnt vmcnt(3)" ::: "memory");
    } else {
      asm volatile("s_waitcnt vmcnt(0)" ::: "memory");
    }
    __builtin_amdgcn_s_barrier();

    short8 af[WM], bfr[WN];
    #pragma unroll
    for (int m = 0; m < WM; ++m)
      af[m] = *(const short8*)&lds[cur][(wr * WM + m) * 1024 + lane * 16];
    #pragma unroll
    for (int n = 0; n < WN; ++n)
      bfr[n] = *(const short8*)&lds[cur][(AF + wc * WN + n) * 1024 + lane * 16];
    #pragma unroll
    for (int m = 0; m < WM; ++m)
      #pragma unroll
      for (int n = 0; n < WN; ++n)
        acc[m][n] = __builtin_amdgcn_mfma_f32_16x16x32_bf16(af[m], bfr[n], acc[m][n], 0, 0, 0);

    __builtin_amdgcn_s_barrier();
    if (k0 + 32 >= K) break;
  }

  const int a = lane & 15, hq = lane >> 4;
  #pragma unroll
  for (int m = 0; m < WM; ++m) {
    #pragma unroll
    for (int n = 0; n < WN; ++n) {
      int c = tN + wc * (WN * 16) + n * 16 + a;
      float bv = bias[c];
      int r0 = tM + wr * (WM * 16) + m * 16 + hq * 4;
      #pragma unroll
      for (int r = 0; r < 4; ++r)
        O[(size_t)(r0 + r) * N + c] = acc[m][n][r] + bv;
    }
  }
}

// ---------------------------------------------------------------------------
// Flash attention v2: QBLK=128 (2 Q-fragments/wave), KVBLK=128, 4 waves.
// Fixed-base softmax; l via ones-MFMA (register-aligned with O rows).
// LDS 48KB: P [0,18432) overlays dead Q [0,16384) + K-head (extra barrier
// after QK); K [16384,32768); V [32768,49152). 3 blocks/CU.
// grid (BH=32, 16), qt = yb<8 ? yb : 23-yb (balanced: pairs sum 17 tiles).
// ---------------------------------------------------------------------------
__global__ __launch_bounds__(256) void attn_mfma(
    const unsigned short* __restrict__ Qg, const unsigned short* __restrict__ Kg,
    const unsigned short* __restrict__ Vtg, unsigned short* __restrict__ Y)
{
  __shared__ alignas(16) unsigned char lds[49152];
  const int bh = blockIdx.x;
  const int yb = blockIdx.y;
  const int qt = (yb < 8) ? yb : 23 - yb;
  const int tid = threadIdx.x, wave = tid >> 6, lane = tid & 63;
  const int a = lane & 15, h = lane >> 4;
  const int a7 = a & 7;
  const int q0 = qt * 128;
  const unsigned short* Qp = Qg + (size_t)bh * Tn * HSn;
  const unsigned short* Kp = Kg + (size_t)bh * Tn * HSn;
  const unsigned short* Vp = Vtg + (size_t)bh * HSn * Tn;   // [64][2048]
  const int pbase = wave * 4608;                            // P over Q region

  // stage Q tile: 128 rows x 128B swizzled (wave w stages its own 32 rows)
  #pragma unroll
  for (int i = 0; i < 4; ++i) {
    int r8 = wave * 32 + i * 8;
    int row = r8 + (lane >> 3);
    int ch = (lane & 7) ^ (row & 7);
    gload_lds16(Qp + (size_t)(q0 + row) * HSn + ch * 8, &lds[r8 * 128]);
  }
  __syncthreads();
  short8 qfA[2], qfB[2];
  #pragma unroll
  for (int ks = 0; ks < 2; ++ks) {
    int rowA = wave * 32 + a;
    int ch = (ks * 4 + h) ^ (rowA & 7);
    qfA[ks] = *(const short8*)&lds[rowA * 128 + ch * 16];
    qfB[ks] = *(const short8*)&lds[(rowA + 16) * 128 + ch * 16];
  }

  short8 ones;
  #pragma unroll
  for (int j = 0; j < 8; ++j) ones[j] = (short)0x3F80;   // bf16 1.0

  f32x4 oA[4] = {}, oB[4] = {};
  f32x4 lA = {}, lB = {};

  for (int p = 0; p <= qt; ++p) {
    const int kv0 = p * 128;
    const bool masked = (p == qt);
    __syncthreads();
    // stage K: 128 rows x 128B; V: 64 d-rows x 256B
    #pragma unroll
    for (int i = 0; i < 4; ++i) {
      int r8 = wave * 32 + i * 8;
      int row = r8 + (lane >> 3);
      int ch = (lane & 7) ^ (row & 7);
      gload_lds16(Kp + (size_t)(kv0 + row) * HSn + ch * 8, &lds[16384 + r8 * 128]);
    }
    #pragma unroll
    for (int i = 0; i < 4; ++i) {
      int d4 = wave * 16 + i * 4;
      int d = d4 + (lane >> 4);
      int ch = (lane & 15) ^ (d & 7);
      gload_lds16(Vp + (size_t)d * Tn + kv0 + ch * 8, &lds[32768 + d4 * 256]);
    }
    __syncthreads();

    // S^T = K Q^T for both q-fragments
    f32x4 sA[8] = {}, sB[8] = {};
    __builtin_amdgcn_s_setprio(1);
    #pragma unroll
    for (int ks = 0; ks < 2; ++ks)
      #pragma unroll
      for (int n = 0; n < 8; ++n) {
        int kr = n * 16 + a;
        int ch = (ks * 4 + h) ^ a7;
        short8 kf = *(const short8*)&lds[16384 + kr * 128 + ch * 16];
        sA[n] = __builtin_amdgcn_mfma_f32_16x16x32_bf16(kf, qfA[ks], sA[n], 0, 0, 0);
        sB[n] = __builtin_amdgcn_mfma_f32_16x16x32_bf16(kf, qfB[ks], sB[n], 0, 0, 0);
      }
    __builtin_amdgcn_s_setprio(0);

    if (masked) {
      #pragma unroll
      for (int n = 0; n < 8; ++n)
        #pragma unroll
        for (int r = 0; r < 4; ++r) {
          int kv = n * 16 + h * 4 + r;
          if (kv > (wave * 32 + a)) sA[n][r] = -1e30f;
          if (kv > (wave * 32 + 16 + a)) sB[n][r] = -1e30f;
        }
    }
    #pragma unroll
    for (int n = 0; n < 8; ++n)
      #pragma unroll
      for (int r = 0; r < 4; ++r) {
        sA[n][r] = fexp2(sA[n][r]);
        sB[n][r] = fexp2(sB[n][r]);
      }

    __syncthreads();   // all waves done reading K before P overwrites K-head

    // PV in two 64-kv halves; l accumulated via ones-MFMA
    #pragma unroll
    for (int hp = 0; hp < 2; ++hp) {
      #pragma unroll
      for (int nn = 0; nn < 4; ++nn) {
        int n = hp * 4 + nn;
        uint2 w2;
        w2.x = (unsigned)f2bf(sA[n][0]) | ((unsigned)f2bf(sA[n][1]) << 16);
        w2.y = (unsigned)f2bf(sA[n][2]) | ((unsigned)f2bf(sA[n][3]) << 16);
        *(uint2*)&lds[pbase + (a * 36 + nn * 8 + h * 2) * 4] = w2;
        uint2 v2;
        v2.x = (unsigned)f2bf(sB[n][0]) | ((unsigned)f2bf(sB[n][1]) << 16);
        v2.y = (unsigned)f2bf(sB[n][2]) | ((unsigned)f2bf(sB[n][3]) << 16);
        *(uint2*)&lds[pbase + 2304 + (a * 36 + nn * 8 + h * 2) * 4] = v2;
      }
      __builtin_amdgcn_s_setprio(1);
      #pragma unroll
      for (int ks = 0; ks < 2; ++ks) {
        short8 paA = *(const short8*)&lds[pbase + (a * 36 + ks * 16 + h * 4) * 4];
        short8 paB = *(const short8*)&lds[pbase + 2304 + (a * 36 + ks * 16 + h * 4) * 4];
        lA = __builtin_amdgcn_mfma_f32_16x16x32_bf16(paA, ones, lA, 0, 0, 0);
        lB = __builtin_amdgcn_mfma_f32_16x16x32_bf16(paB, ones, lB, 0, 0, 0);
        #pragma unroll
        for (int n = 0; n < 4; ++n) {
          int d = n * 16 + a;
          int ch = (hp * 8 + ks * 4 + h) ^ a7;
          short8 vf = *(const short8*)&lds[32768 + d * 256 + ch * 16];
          oA[n] = __builtin_amdgcn_mfma_f32_16x16x32_bf16(paA, vf, oA[n], 0, 0, 0);
          oB[n] = __builtin_amdgcn_mfma_f32_16x16x32_bf16(paB, vf, oB[n], 0, 0, 0);
        }
      }
      __builtin_amdgcn_s_setprio(0);
    }
  }

  // epilogue: l is register-aligned with o rows (row = 4h+r)
  f32x4 invA, invB;
  #pragma unroll
  for (int r = 0; r < 4; ++r) {
    invA[r] = 1.0f / lA[r];
    invB[r] = 1.0f / lB[r];
  }
  const int b = bh >> 4, hd = bh & 15;
  #pragma unroll
  for (int n = 0; n < 4; ++n)
    #pragma unroll
    for (int r = 0; r < 4; ++r) {
      int col = hd * 64 + n * 16 + a;
      int tA = q0 + wave * 32 + 4 * h + r;
      Y[((size_t)(b * Tn + tA)) * Cn + col] = f2bf(oA[n][r] * invA[r]);
      Y[((size_t)(b * Tn + tA + 16)) * Cn + col] = f2bf(oB[n][r] * invB[r]);
    }
}

// ---------------------------------------------------------------------------
extern "C" void kernel_launch(void* const* d_in, const int* in_sizes, int n_in,
                              void* d_out, int out_size, void* d_ws, size_t ws_size,
                              hipStream_t stream) {
  const float* x      = (const float*)d_in[0];
  const float* W_attn = (const float*)d_in[1];
  const float* b_attn = (const float*)d_in[2];
  const float* W_proj = (const float*)d_in[3];
  const float* b_proj = (const float*)d_in[4];
  float* out = (float*)d_out;

  unsigned short* xb  = (unsigned short*)d_ws;          // [4096][1024]
  unsigned short* Wab = xb + (size_t)Mrows * Cn;        // [3072][1024]
  unsigned short* Wpb = Wab + (size_t)3 * Cn * Cn;      // [1024][1024]
  unsigned short* qkv = Wpb + (size_t)Cn * Cn;          // 3 planes of PL
  unsigned short* y   = qkv + 3 * PL;                   // [4096][1024]

  prep_all<<<4096 + 3072 + 1024, 256, 0, stream>>>(x, xb, W_attn, Wab, W_proj, Wpb);

  gemmQKV<<<256, 512, 0, stream>>>(xb, Wab, b_attn, qkv, Cn);

  attn_mfma<<<dim3(Bn * Hn, 16), 256, 0, stream>>>(qkv, qkv + PL, qkv + 2 * PL, y);

  gemmP<4, 2><<<dim3(Cn / 64, Mrows / 128), 256, 0, stream>>>(
      y, Wpb, b_proj, out, Cn, Cn);
}

// Round 14
// 113.048 us; speedup vs baseline: 1.0235x; 1.0235x over previous
//
#include <hip/hip_runtime.h>
#include <hip/hip_bf16.h>

static constexpr int Bn = 2, Tn = 2048, Cn = 1024, Hn = 16, HSn = 64;
static constexpr int Mrows = Bn * Tn;                 // 4096
static constexpr size_t PL = (size_t)Bn * Hn * Tn * HSn;  // one qkv plane (4.19M)

typedef __attribute__((ext_vector_type(8))) short short8;
typedef __attribute__((ext_vector_type(4))) float f32x4;

__device__ __forceinline__ unsigned short f2bf(float f) {
  __hip_bfloat16 h = __float2bfloat16(f);
  return *reinterpret_cast<unsigned short*>(&h);
}

__device__ __forceinline__ float fexp2(float x) {
  return __builtin_amdgcn_exp2f(x);
}

__device__ __forceinline__ void gload_lds16(const void* g, void* l) {
  __builtin_amdgcn_global_load_lds(
      (const __attribute__((address_space(1))) void*)g,
      (__attribute__((address_space(3))) void*)l, 16, 0, 0);
}

// qscale folded into Q plane at GEMM epilogue: (1/sqrt(64)) * log2(e)
#define QSC 0.18033688011112042591999058512524f

// ---------------------------------------------------------------------------
// merged prep kernel (unchanged)
// ---------------------------------------------------------------------------
__global__ __launch_bounds__(256) void prep_all(
    const float* __restrict__ x, unsigned short* __restrict__ xb,
    const float* __restrict__ Wa, unsigned short* __restrict__ Wab,
    const float* __restrict__ Wp, unsigned short* __restrict__ Wpb)
{
  const int bid = blockIdx.x, tid = threadIdx.x;
  if (bid < 4096) {
    int i = bid * 256 + tid;
    float4 v = ((const float4*)x)[i];
    ushort4 o;
    o.x = f2bf(v.x); o.y = f2bf(v.y); o.z = f2bf(v.z); o.w = f2bf(v.w);
    ((ushort4*)xb)[i] = o;
    return;
  }
  __shared__ float tile[32][33];
  const float* src; unsigned short* dst; int R, Cc, tb;
  if (bid < 4096 + 3072) { src = Wa; dst = Wab; R = Cn; Cc = 3 * Cn; tb = bid - 4096; }
  else                   { src = Wp; dst = Wpb; R = Cn; Cc = Cn;     tb = bid - 4096 - 3072; }
  const int nbx = Cc / 32;
  const int bx = tb % nbx, by = tb / nbx;
  const int tx = tid & 31, ty = tid >> 5;
  const int c0 = bx * 32, r0 = by * 32;
  #pragma unroll
  for (int i = 0; i < 4; ++i)
    tile[ty + 8 * i][tx] = src[(size_t)(r0 + ty + 8 * i) * Cc + c0 + tx];
  __syncthreads();
  #pragma unroll
  for (int i = 0; i < 4; ++i)
    dst[(size_t)(c0 + ty + 8 * i) * R + r0 + tx] = f2bf(tile[tx][ty + 8 * i]);
}

// ---------------------------------------------------------------------------
// QKV GEMM, 256x192 tile, grid 256 (1/CU), XCD swizzle (unchanged from R11)
// ---------------------------------------------------------------------------
__global__ __launch_bounds__(512) void gemmQKV(
    const unsigned short* __restrict__ A, const unsigned short* __restrict__ Bt,
    const float* __restrict__ bias, unsigned short* __restrict__ qkv, int K)
{
  constexpr int NSTEP = 1024 / 64;     // 16 K-steps
  constexpr int AF = 32;               // 16 mg x 2 ks
  constexpr int BF = 24;               // 12 ng x 2 ks
  __shared__ alignas(16) unsigned char lds[2][(AF + BF) * 1024];

  const int tid = threadIdx.x, wave = tid >> 6, lane = tid & 63;
  const int wr = wave >> 2, wc = wave & 3;            // 2 x 4 wave grid
  const int orig = blockIdx.x;
  const int swz = (orig & 7) * 32 + (orig >> 3);
  const int bx = swz & 15, by = swz >> 4;
  const int tM = by * 256, tN = bx * 192;

  auto STAGE = [&](int buf, int k0) {
    #pragma unroll
    for (int i = 0; i < 7; ++i) {
      int f = wave * 7 + i;
      const unsigned short* g;
      int off;
      if (f < AF) {
        int mg = f >> 1, ks = f & 1;
        g = A + (size_t)(tM + mg * 16 + (lane & 15)) * K + k0 + ks * 32 + (lane >> 4) * 8;
        off = f * 1024;
      } else {
        int fg = f - AF;
        int ng = fg >> 1, ks = fg & 1;
        g = Bt + (size_t)(tN + ng * 16 + (lane & 15)) * K + k0 + ks * 32 + (lane >> 4) * 8;
        off = AF * 1024 + fg * 1024;
      }
      gload_lds16(g, &lds[buf][off]);
    }
  };

  f32x4 acc[8][3] = {};

  STAGE(0, 0);
  STAGE(1, 64);

  for (int t = 0; t < NSTEP; ++t) {
    if (t == NSTEP - 1)
      asm volatile("s_waitcnt vmcnt(0)" ::: "memory");
    else
      asm volatile("s_waitcnt vmcnt(7)" ::: "memory");
    __builtin_amdgcn_s_barrier();

    const int cur = t & 1;
    short8 af[8][2], bfr[3][2];
    #pragma unroll
    for (int ks = 0; ks < 2; ++ks) {
      #pragma unroll
      for (int m = 0; m < 8; ++m)
        af[m][ks] = *(const short8*)&lds[cur][((wr * 8 + m) * 2 + ks) * 1024 + lane * 16];
      #pragma unroll
      for (int n = 0; n < 3; ++n)
        bfr[n][ks] = *(const short8*)&lds[cur][AF * 1024 + ((wc * 3 + n) * 2 + ks) * 1024 + lane * 16];
    }
    asm volatile("s_waitcnt lgkmcnt(0)" ::: "memory");
    __builtin_amdgcn_sched_barrier(0);
    __builtin_amdgcn_s_barrier();

    if (t + 2 < NSTEP) STAGE(cur, (t + 2) * 64);

    __builtin_amdgcn_s_setprio(1);
    #pragma unroll
    for (int ks = 0; ks < 2; ++ks)
      #pragma unroll
      for (int m = 0; m < 8; ++m)
        #pragma unroll
        for (int n = 0; n < 3; ++n)
          acc[m][n] = __builtin_amdgcn_mfma_f32_16x16x32_bf16(af[m][ks], bfr[n][ks], acc[m][n], 0, 0, 0);
    __builtin_amdgcn_s_setprio(0);
  }

  const int a = lane & 15, hq = lane >> 4;
  #pragma unroll
  for (int m = 0; m < 8; ++m) {
    #pragma unroll
    for (int n = 0; n < 3; ++n) {
      int c = tN + wc * 48 + n * 16 + a;
      float bv = bias[c];
      int which = c >> 10;
      int cc = c & 1023, hh = cc >> 6, d = cc & 63;
      int row0 = tM + wr * 128 + m * 16 + hq * 4;
      int b = row0 >> 11, t0 = row0 & 2047;
      int bh = b * Hn + hh;
      if (which == 2) {
        ushort4 pk;
        pk.x = f2bf(acc[m][n][0] + bv);
        pk.y = f2bf(acc[m][n][1] + bv);
        pk.z = f2bf(acc[m][n][2] + bv);
        pk.w = f2bf(acc[m][n][3] + bv);
        *(ushort4*)&qkv[2 * PL + ((size_t)bh * HSn + d) * Tn + t0] = pk;
      } else {
        float sc = (which == 0) ? QSC : 1.0f;
        #pragma unroll
        for (int r = 0; r < 4; ++r) {
          float v = (acc[m][n][r] + bv) * sc;
          qkv[(size_t)which * PL + ((size_t)bh * Tn + t0 + r) * HSn + d] = f2bf(v);
        }
      }
    }
  }
}

// ---------------------------------------------------------------------------
// proj GEMM (unchanged R7 structure)
// ---------------------------------------------------------------------------
template <int WM, int WN>
__global__ __launch_bounds__(256) void gemmP(
    const unsigned short* __restrict__ A, const unsigned short* __restrict__ Bt,
    const float* __restrict__ bias, float* __restrict__ O, int N, int K)
{
  constexpr int BM = WM * 32, BNt = WN * 32;
  constexpr int AF = BM / 16;
  constexpr int BF = BNt / 16;
  constexpr int NF = AF + BF;
  constexpr int PW = NF / 4;
  static_assert(PW == 3, "vmcnt literal");
  __shared__ alignas(16) unsigned char lds[2][NF * 1024];

  const int tid = threadIdx.x, wave = tid >> 6, lane = tid & 63;
  const int wr = wave >> 1, wc = wave & 1;
  const int tM = blockIdx.y * BM, tN = blockIdx.x * BNt;

  auto STAGE = [&](int buf, int k0) {
    #pragma unroll
    for (int i = 0; i < PW; ++i) {
      int f = wave * PW + i;
      const unsigned short* g;
      if (f < AF)
        g = A + (size_t)(tM + f * 16 + (lane & 15)) * K + k0 + (lane >> 4) * 8;
      else
        g = Bt + (size_t)(tN + (f - AF) * 16 + (lane & 15)) * K + k0 + (lane >> 4) * 8;
      gload_lds16(g, &lds[buf][f * 1024]);
    }
  };

  f32x4 acc[WM][WN] = {};

  STAGE(0, 0);
  for (int t = 0, k0 = 0;; ++t, k0 += 32) {
    const int cur = t & 1;
    if (k0 + 32 < K) {
      STAGE(cur ^ 1, k0 + 32);
      asm volatile("s_waitcnt vmcnt(3)" ::: "memory");
    } else {
      asm volatile("s_waitcnt vmcnt(0)" ::: "memory");
    }
    __builtin_amdgcn_s_barrier();

    short8 af[WM], bfr[WN];
    #pragma unroll
    for (int m = 0; m < WM; ++m)
      af[m] = *(const short8*)&lds[cur][(wr * WM + m) * 1024 + lane * 16];
    #pragma unroll
    for (int n = 0; n < WN; ++n)
      bfr[n] = *(const short8*)&lds[cur][(AF + wc * WN + n) * 1024 + lane * 16];
    #pragma unroll
    for (int m = 0; m < WM; ++m)
      #pragma unroll
      for (int n = 0; n < WN; ++n)
        acc[m][n] = __builtin_amdgcn_mfma_f32_16x16x32_bf16(af[m], bfr[n], acc[m][n], 0, 0, 0);

    __builtin_amdgcn_s_barrier();
    if (k0 + 32 >= K) break;
  }

  const int a = lane & 15, hq = lane >> 4;
  #pragma unroll
  for (int m = 0; m < WM; ++m) {
    #pragma unroll
    for (int n = 0; n < WN; ++n) {
      int c = tN + wc * (WN * 16) + n * 16 + a;
      float bv = bias[c];
      int r0 = tM + wr * (WM * 16) + m * 16 + hq * 4;
      #pragma unroll
      for (int r = 0; r < 4; ++r)
        O[(size_t)(r0 + r) * N + c] = acc[m][n][r] + bv;
    }
  }
}

// ---------------------------------------------------------------------------
// Flash attention v3: QBLK=64 (4 waves x 16 q-rows), KVBLK=64,
// K/V DOUBLE-BUFFERED with 2-tile-deep prefetch + counted vmcnt(4)
// (gemm256 recipe applied to attn). Fixed-base softmax; l via ones-MFMA.
// LDS 50176B (3 blocks/CU): Q[0,8K) | K dbuf [8K,24K) | V dbuf [24K,40K) |
// P per-wave [40960 + wave*2304). 2 raw barriers per iter; stages for tile
// t+2 issue after the reads-done barrier and stay in flight across iter t+1.
// grid (BH=32, 32 serpentine-remapped qt).
// ---------------------------------------------------------------------------
__global__ __launch_bounds__(256) void attn_mfma(
    const unsigned short* __restrict__ Qg, const unsigned short* __restrict__ Kg,
    const unsigned short* __restrict__ Vtg, unsigned short* __restrict__ Y)
{
  __shared__ alignas(16) unsigned char lds[50176];
  const int bh = blockIdx.x;
  const int yb = blockIdx.y;
  const int kq = yb >> 3, jq = yb & 7;
  const int qt = kq * 8 + ((kq & 1) ? (7 - jq) : jq);   // balanced causal remap
  const int tid = threadIdx.x, wave = tid >> 6, lane = tid & 63;
  const int a = lane & 15, h = lane >> 4;
  const int q0 = qt * 64;
  const unsigned short* Qp = Qg + (size_t)bh * Tn * HSn;
  const unsigned short* Kp = Kg + (size_t)bh * Tn * HSn;
  const unsigned short* Vp = Vtg + (size_t)bh * HSn * Tn;   // [64][2048]
  const int pbase = 40960 + wave * 2304;
  const int qglob = wave * 16 + a;

  auto STAGE_K = [&](int kb, int kv0) {
    #pragma unroll
    for (int i = 0; i < 2; ++i) {
      int r8 = wave * 16 + i * 8;
      int row = r8 + (lane >> 3);
      int ch = (lane & 7) ^ (row & 7);
      gload_lds16(Kp + (size_t)(kv0 + row) * HSn + ch * 8,
                  &lds[8192 + kb * 8192 + r8 * 128]);
    }
  };
  auto STAGE_V = [&](int vb, int kv0) {
    #pragma unroll
    for (int i = 0; i < 2; ++i) {
      int r8 = wave * 16 + i * 8;
      int row = r8 + (lane >> 3);
      int ch = (lane & 7) ^ (row & 7);
      gload_lds16(Vp + (size_t)row * Tn + kv0 + ch * 8,
                  &lds[24576 + vb * 8192 + r8 * 128]);
    }
  };

  // prologue: Q (wave-local rows), then K/V for tiles 0 and 1
  #pragma unroll
  for (int i = 0; i < 2; ++i) {
    int r8 = wave * 16 + i * 8;
    int row = r8 + (lane >> 3);
    int ch = (lane & 7) ^ (row & 7);
    gload_lds16(Qp + (size_t)(q0 + row) * HSn + ch * 8, &lds[r8 * 128]);
  }
  STAGE_K(0, 0);
  STAGE_V(0, 0);
  if (qt >= 1) {
    STAGE_K(1, 64);
    STAGE_V(1, 64);
    asm volatile("s_waitcnt vmcnt(8)" ::: "memory");   // Q landed
  } else {
    asm volatile("s_waitcnt vmcnt(4)" ::: "memory");   // Q landed
  }

  short8 qf[2];
  #pragma unroll
  for (int ks = 0; ks < 2; ++ks) {
    int row = wave * 16 + a;
    int ch = (ks * 4 + h) ^ (row & 7);
    qf[ks] = *(const short8*)&lds[row * 128 + ch * 16];   // own wave's rows
  }

  short8 ones;
  #pragma unroll
  for (int j = 0; j < 8; ++j) ones[j] = (short)0x3F80;    // bf16 1.0

  f32x4 o[4] = {};
  f32x4 lacc = {};

  for (int t = 0; t <= qt; ++t) {
    const int kb = t & 1;
    if (t == qt)
      asm volatile("s_waitcnt vmcnt(0)" ::: "memory");
    else
      asm volatile("s_waitcnt vmcnt(4)" ::: "memory");   // tile t landed; t+1 in flight
    __builtin_amdgcn_s_barrier();

    const int kbase = 8192 + kb * 8192;
    const int vbase = 24576 + kb * 8192;

    // S^T = K Q^T : lane (a,h) holds S[kv = n*16+4h+r][q = qglob]
    f32x4 s[4] = {};
    __builtin_amdgcn_s_setprio(1);
    #pragma unroll
    for (int ks = 0; ks < 2; ++ks)
      #pragma unroll
      for (int n = 0; n < 4; ++n) {
        int kr = n * 16 + a;
        int ch = (ks * 4 + h) ^ (kr & 7);
        short8 kf = *(const short8*)&lds[kbase + kr * 128 + ch * 16];
        s[n] = __builtin_amdgcn_mfma_f32_16x16x32_bf16(kf, qf[ks], s[n], 0, 0, 0);
      }
    __builtin_amdgcn_s_setprio(0);

    if (t == qt) {
      #pragma unroll
      for (int n = 0; n < 4; ++n)
        #pragma unroll
        for (int r = 0; r < 4; ++r)
          if ((n * 16 + h * 4 + r) > qglob) s[n][r] = -1e30f;
    }

    // fixed-base softmax: p = exp2(s)
    #pragma unroll
    for (int n = 0; n < 4; ++n)
      #pragma unroll
      for (int r = 0; r < 4; ++r) s[n][r] = fexp2(s[n][r]);

    // P -> LDS bf16 (lane-local pack)
    #pragma unroll
    for (int n = 0; n < 4; ++n) {
      uint2 w2;
      w2.x = (unsigned)f2bf(s[n][0]) | ((unsigned)f2bf(s[n][1]) << 16);
      w2.y = (unsigned)f2bf(s[n][2]) | ((unsigned)f2bf(s[n][3]) << 16);
      *(uint2*)&lds[pbase + (a * 36 + n * 8 + h * 2) * 4] = w2;
    }

    // O += P V ; l += P 1 (ones-MFMA, register-aligned with O rows)
    __builtin_amdgcn_s_setprio(1);
    #pragma unroll
    for (int ks = 0; ks < 2; ++ks) {
      short8 pa = *(const short8*)&lds[pbase + (a * 36 + ks * 16 + h * 4) * 4];
      lacc = __builtin_amdgcn_mfma_f32_16x16x32_bf16(pa, ones, lacc, 0, 0, 0);
      #pragma unroll
      for (int n = 0; n < 4; ++n) {
        int d = n * 16 + a;
        int ch = (ks * 4 + h) ^ (d & 7);
        short8 vf = *(const short8*)&lds[vbase + d * 128 + ch * 16];
        o[n] = __builtin_amdgcn_mfma_f32_16x16x32_bf16(pa, vf, o[n], 0, 0, 0);
      }
    }
    __builtin_amdgcn_s_setprio(0);

    __builtin_amdgcn_s_barrier();          // all waves done reading buf kb
    if (t + 2 <= qt) {
      STAGE_K(kb, (t + 2) * 64);           // lands during iter t+1
      STAGE_V(kb, (t + 2) * 64);
    }
  }

  // epilogue: divide by l (register-aligned), y[b][t][head*64+d] bf16
  f32x4 inv;
  #pragma unroll
  for (int r = 0; r < 4; ++r) inv[r] = 1.0f / lacc[r];
  const int b = bh >> 4, hd = bh & 15;
  #pragma unroll
  for (int n = 0; n < 4; ++n)
    #pragma unroll
    for (int r = 0; r < 4; ++r) {
      int t = q0 + wave * 16 + 4 * h + r;
      int col = hd * 64 + n * 16 + a;
      Y[((size_t)(b * Tn + t)) * Cn + col] = f2bf(o[n][r] * inv[r]);
    }
}

// ---------------------------------------------------------------------------
extern "C" void kernel_launch(void* const* d_in, const int* in_sizes, int n_in,
                              void* d_out, int out_size, void* d_ws, size_t ws_size,
                              hipStream_t stream) {
  const float* x      = (const float*)d_in[0];
  const float* W_attn = (const float*)d_in[1];
  const float* b_attn = (const float*)d_in[2];
  const float* W_proj = (const float*)d_in[3];
  const float* b_proj = (const float*)d_in[4];
  float* out = (float*)d_out;

  unsigned short* xb  = (unsigned short*)d_ws;          // [4096][1024]
  unsigned short* Wab = xb + (size_t)Mrows * Cn;        // [3072][1024]
  unsigned short* Wpb = Wab + (size_t)3 * Cn * Cn;      // [1024][1024]
  unsigned short* qkv = Wpb + (size_t)Cn * Cn;          // 3 planes of PL
  unsigned short* y   = qkv + 3 * PL;                   // [4096][1024]

  prep_all<<<4096 + 3072 + 1024, 256, 0, stream>>>(x, xb, W_attn, Wab, W_proj, Wpb);

  gemmQKV<<<256, 512, 0, stream>>>(xb, Wab, b_attn, qkv, Cn);

  attn_mfma<<<dim3(Bn * Hn, Tn / 64), 256, 0, stream>>>(qkv, qkv + PL, qkv + 2 * PL, y);

  gemmP<4, 2><<<dim3(Cn / 64, Mrows / 128), 256, 0, stream>>>(
      y, Wpb, b_proj, out, Cn, Cn);
}

// Round 15
// 108.579 us; speedup vs baseline: 1.0656x; 1.0412x over previous
//
#include <hip/hip_runtime.h>
#include <hip/hip_bf16.h>

static constexpr int Bn = 2, Tn = 2048, Cn = 1024, Hn = 16, HSn = 64;
static constexpr int Mrows = Bn * Tn;                 // 4096
static constexpr size_t PL = (size_t)Bn * Hn * Tn * HSn;  // one qkv plane (4.19M)

typedef __attribute__((ext_vector_type(8))) short short8;
typedef __attribute__((ext_vector_type(4))) float f32x4;

__device__ __forceinline__ unsigned short f2bf(float f) {
  __hip_bfloat16 h = __float2bfloat16(f);
  return *reinterpret_cast<unsigned short*>(&h);
}

__device__ __forceinline__ float fexp2(float x) {
  return __builtin_amdgcn_exp2f(x);
}

__device__ __forceinline__ void gload_lds16(const void* g, void* l) {
  __builtin_amdgcn_global_load_lds(
      (const __attribute__((address_space(1))) void*)g,
      (__attribute__((address_space(3))) void*)l, 16, 0, 0);
}

// qscale folded into Q plane at GEMM epilogue: (1/sqrt(64)) * log2(e)
#define QSC 0.18033688011112042591999058512524f

// ---------------------------------------------------------------------------
// merged prep kernel (unchanged)
// ---------------------------------------------------------------------------
__global__ __launch_bounds__(256) void prep_all(
    const float* __restrict__ x, unsigned short* __restrict__ xb,
    const float* __restrict__ Wa, unsigned short* __restrict__ Wab,
    const float* __restrict__ Wp, unsigned short* __restrict__ Wpb)
{
  const int bid = blockIdx.x, tid = threadIdx.x;
  if (bid < 4096) {
    int i = bid * 256 + tid;
    float4 v = ((const float4*)x)[i];
    ushort4 o;
    o.x = f2bf(v.x); o.y = f2bf(v.y); o.z = f2bf(v.z); o.w = f2bf(v.w);
    ((ushort4*)xb)[i] = o;
    return;
  }
  __shared__ float tile[32][33];
  const float* src; unsigned short* dst; int R, Cc, tb;
  if (bid < 4096 + 3072) { src = Wa; dst = Wab; R = Cn; Cc = 3 * Cn; tb = bid - 4096; }
  else                   { src = Wp; dst = Wpb; R = Cn; Cc = Cn;     tb = bid - 4096 - 3072; }
  const int nbx = Cc / 32;
  const int bx = tb % nbx, by = tb / nbx;
  const int tx = tid & 31, ty = tid >> 5;
  const int c0 = bx * 32, r0 = by * 32;
  #pragma unroll
  for (int i = 0; i < 4; ++i)
    tile[ty + 8 * i][tx] = src[(size_t)(r0 + ty + 8 * i) * Cc + c0 + tx];
  __syncthreads();
  #pragma unroll
  for (int i = 0; i < 4; ++i)
    dst[(size_t)(c0 + ty + 8 * i) * R + r0 + tx] = f2bf(tile[tx][ty + 8 * i]);
}

// ---------------------------------------------------------------------------
// QKV GEMM, 256x192 tile, grid 256 (1/CU), XCD swizzle (unchanged from R11)
// ---------------------------------------------------------------------------
__global__ __launch_bounds__(512) void gemmQKV(
    const unsigned short* __restrict__ A, const unsigned short* __restrict__ Bt,
    const float* __restrict__ bias, unsigned short* __restrict__ qkv, int K)
{
  constexpr int NSTEP = 1024 / 64;     // 16 K-steps
  constexpr int AF = 32;               // 16 mg x 2 ks
  constexpr int BF = 24;               // 12 ng x 2 ks
  __shared__ alignas(16) unsigned char lds[2][(AF + BF) * 1024];

  const int tid = threadIdx.x, wave = tid >> 6, lane = tid & 63;
  const int wr = wave >> 2, wc = wave & 3;            // 2 x 4 wave grid
  const int orig = blockIdx.x;
  const int swz = (orig & 7) * 32 + (orig >> 3);
  const int bx = swz & 15, by = swz >> 4;
  const int tM = by * 256, tN = bx * 192;

  auto STAGE = [&](int buf, int k0) {
    #pragma unroll
    for (int i = 0; i < 7; ++i) {
      int f = wave * 7 + i;
      const unsigned short* g;
      int off;
      if (f < AF) {
        int mg = f >> 1, ks = f & 1;
        g = A + (size_t)(tM + mg * 16 + (lane & 15)) * K + k0 + ks * 32 + (lane >> 4) * 8;
        off = f * 1024;
      } else {
        int fg = f - AF;
        int ng = fg >> 1, ks = fg & 1;
        g = Bt + (size_t)(tN + ng * 16 + (lane & 15)) * K + k0 + ks * 32 + (lane >> 4) * 8;
        off = AF * 1024 + fg * 1024;
      }
      gload_lds16(g, &lds[buf][off]);
    }
  };

  f32x4 acc[8][3] = {};

  STAGE(0, 0);
  STAGE(1, 64);

  for (int t = 0; t < NSTEP; ++t) {
    if (t == NSTEP - 1)
      asm volatile("s_waitcnt vmcnt(0)" ::: "memory");
    else
      asm volatile("s_waitcnt vmcnt(7)" ::: "memory");
    __builtin_amdgcn_s_barrier();

    const int cur = t & 1;
    short8 af[8][2], bfr[3][2];
    #pragma unroll
    for (int ks = 0; ks < 2; ++ks) {
      #pragma unroll
      for (int m = 0; m < 8; ++m)
        af[m][ks] = *(const short8*)&lds[cur][((wr * 8 + m) * 2 + ks) * 1024 + lane * 16];
      #pragma unroll
      for (int n = 0; n < 3; ++n)
        bfr[n][ks] = *(const short8*)&lds[cur][AF * 1024 + ((wc * 3 + n) * 2 + ks) * 1024 + lane * 16];
    }
    asm volatile("s_waitcnt lgkmcnt(0)" ::: "memory");
    __builtin_amdgcn_sched_barrier(0);
    __builtin_amdgcn_s_barrier();

    if (t + 2 < NSTEP) STAGE(cur, (t + 2) * 64);

    __builtin_amdgcn_s_setprio(1);
    #pragma unroll
    for (int ks = 0; ks < 2; ++ks)
      #pragma unroll
      for (int m = 0; m < 8; ++m)
        #pragma unroll
        for (int n = 0; n < 3; ++n)
          acc[m][n] = __builtin_amdgcn_mfma_f32_16x16x32_bf16(af[m][ks], bfr[n][ks], acc[m][n], 0, 0, 0);
    __builtin_amdgcn_s_setprio(0);
  }

  const int a = lane & 15, hq = lane >> 4;
  #pragma unroll
  for (int m = 0; m < 8; ++m) {
    #pragma unroll
    for (int n = 0; n < 3; ++n) {
      int c = tN + wc * 48 + n * 16 + a;
      float bv = bias[c];
      int which = c >> 10;
      int cc = c & 1023, hh = cc >> 6, d = cc & 63;
      int row0 = tM + wr * 128 + m * 16 + hq * 4;
      int b = row0 >> 11, t0 = row0 & 2047;
      int bh = b * Hn + hh;
      if (which == 2) {
        ushort4 pk;
        pk.x = f2bf(acc[m][n][0] + bv);
        pk.y = f2bf(acc[m][n][1] + bv);
        pk.z = f2bf(acc[m][n][2] + bv);
        pk.w = f2bf(acc[m][n][3] + bv);
        *(ushort4*)&qkv[2 * PL + ((size_t)bh * HSn + d) * Tn + t0] = pk;
      } else {
        float sc = (which == 0) ? QSC : 1.0f;
        #pragma unroll
        for (int r = 0; r < 4; ++r) {
          float v = (acc[m][n][r] + bv) * sc;
          qkv[(size_t)which * PL + ((size_t)bh * Tn + t0 + r) * HSn + d] = f2bf(v);
        }
      }
    }
  }
}

// ---------------------------------------------------------------------------
// proj GEMM (unchanged R7 structure)
// ---------------------------------------------------------------------------
template <int WM, int WN>
__global__ __launch_bounds__(256) void gemmP(
    const unsigned short* __restrict__ A, const unsigned short* __restrict__ Bt,
    const float* __restrict__ bias, float* __restrict__ O, int N, int K)
{
  constexpr int BM = WM * 32, BNt = WN * 32;
  constexpr int AF = BM / 16;
  constexpr int BF = BNt / 16;
  constexpr int NF = AF + BF;
  constexpr int PW = NF / 4;
  static_assert(PW == 3, "vmcnt literal");
  __shared__ alignas(16) unsigned char lds[2][NF * 1024];

  const int tid = threadIdx.x, wave = tid >> 6, lane = tid & 63;
  const int wr = wave >> 1, wc = wave & 1;
  const int tM = blockIdx.y * BM, tN = blockIdx.x * BNt;

  auto STAGE = [&](int buf, int k0) {
    #pragma unroll
    for (int i = 0; i < PW; ++i) {
      int f = wave * PW + i;
      const unsigned short* g;
      if (f < AF)
        g = A + (size_t)(tM + f * 16 + (lane & 15)) * K + k0 + (lane >> 4) * 8;
      else
        g = Bt + (size_t)(tN + (f - AF) * 16 + (lane & 15)) * K + k0 + (lane >> 4) * 8;
      gload_lds16(g, &lds[buf][f * 1024]);
    }
  };

  f32x4 acc[WM][WN] = {};

  STAGE(0, 0);
  for (int t = 0, k0 = 0;; ++t, k0 += 32) {
    const int cur = t & 1;
    if (k0 + 32 < K) {
      STAGE(cur ^ 1, k0 + 32);
      asm volatile("s_waitcnt vmcnt(3)" ::: "memory");
    } else {
      asm volatile("s_waitcnt vmcnt(0)" ::: "memory");
    }
    __builtin_amdgcn_s_barrier();

    short8 af[WM], bfr[WN];
    #pragma unroll
    for (int m = 0; m < WM; ++m)
      af[m] = *(const short8*)&lds[cur][(wr * WM + m) * 1024 + lane * 16];
    #pragma unroll
    for (int n = 0; n < WN; ++n)
      bfr[n] = *(const short8*)&lds[cur][(AF + wc * WN + n) * 1024 + lane * 16];
    #pragma unroll
    for (int m = 0; m < WM; ++m)
      #pragma unroll
      for (int n = 0; n < WN; ++n)
        acc[m][n] = __builtin_amdgcn_mfma_f32_16x16x32_bf16(af[m], bfr[n], acc[m][n], 0, 0, 0);

    __builtin_amdgcn_s_barrier();
    if (k0 + 32 >= K) break;
  }

  const int a = lane & 15, hq = lane >> 4;
  #pragma unroll
  for (int m = 0; m < WM; ++m) {
    #pragma unroll
    for (int n = 0; n < WN; ++n) {
      int c = tN + wc * (WN * 16) + n * 16 + a;
      float bv = bias[c];
      int r0 = tM + wr * (WM * 16) + m * 16 + hq * 4;
      #pragma unroll
      for (int r = 0; r < 4; ++r)
        O[(size_t)(r0 + r) * N + c] = acc[m][n][r] + bv;
    }
  }
}

// ---------------------------------------------------------------------------
// Flash attention v4: uniform-duration blocks. Each block handles TWO
// complementary q-tiles (qt = yb and qt = 31-yb) -> every block runs exactly
// 33 inner iterations; grid (32 bh, 16) = 512 equal blocks = 2/CU resident
// for the whole kernel (no drain tail). Inner structure = R14 pipeline:
// QBLK=64, KVBLK=64, K/V double-buffered, 2-deep counted vmcnt(4),
// fixed-base softmax, l via ones-MFMA.
// LDS 50176B: Q[0,8K) | K dbuf [8K,24K) | V dbuf [24K,40K) | P per-wave.
// ---------------------------------------------------------------------------
__global__ __launch_bounds__(256) void attn_mfma(
    const unsigned short* __restrict__ Qg, const unsigned short* __restrict__ Kg,
    const unsigned short* __restrict__ Vtg, unsigned short* __restrict__ Y)
{
  __shared__ alignas(16) unsigned char lds[50176];
  const int bh = blockIdx.x;
  const int yb = blockIdx.y;                            // 0..15
  const int tid = threadIdx.x, wave = tid >> 6, lane = tid & 63;
  const int a = lane & 15, h = lane >> 4;
  const unsigned short* Qp = Qg + (size_t)bh * Tn * HSn;
  const unsigned short* Kp = Kg + (size_t)bh * Tn * HSn;
  const unsigned short* Vp = Vtg + (size_t)bh * HSn * Tn;   // [64][2048]
  const int pbase = 40960 + wave * 2304;
  const int qglob = wave * 16 + a;
  const int b = bh >> 4, hd = bh & 15;

  auto STAGE_K = [&](int kb, int kv0) {
    #pragma unroll
    for (int i = 0; i < 2; ++i) {
      int r8 = wave * 16 + i * 8;
      int row = r8 + (lane >> 3);
      int ch = (lane & 7) ^ (row & 7);
      gload_lds16(Kp + (size_t)(kv0 + row) * HSn + ch * 8,
                  &lds[8192 + kb * 8192 + r8 * 128]);
    }
  };
  auto STAGE_V = [&](int vb, int kv0) {
    #pragma unroll
    for (int i = 0; i < 2; ++i) {
      int r8 = wave * 16 + i * 8;
      int row = r8 + (lane >> 3);
      int ch = (lane & 7) ^ (row & 7);
      gload_lds16(Vp + (size_t)row * Tn + kv0 + ch * 8,
                  &lds[24576 + vb * 8192 + r8 * 128]);
    }
  };

  short8 ones;
  #pragma unroll
  for (int j = 0; j < 8; ++j) ones[j] = (short)0x3F80;    // bf16 1.0

  for (int ph = 0; ph < 2; ++ph) {
    const int qt = ph ? (31 - yb) : yb;
    const int q0 = qt * 64;

    // prologue: Q (wave-local rows), then K/V for tiles 0 and 1
    #pragma unroll
    for (int i = 0; i < 2; ++i) {
      int r8 = wave * 16 + i * 8;
      int row = r8 + (lane >> 3);
      int ch = (lane & 7) ^ (row & 7);
      gload_lds16(Qp + (size_t)(q0 + row) * HSn + ch * 8, &lds[r8 * 128]);
    }
    STAGE_K(0, 0);
    STAGE_V(0, 0);
    if (qt >= 1) {
      STAGE_K(1, 64);
      STAGE_V(1, 64);
      asm volatile("s_waitcnt vmcnt(8)" ::: "memory");   // Q landed
    } else {
      asm volatile("s_waitcnt vmcnt(4)" ::: "memory");   // Q landed
    }

    short8 qf[2];
    #pragma unroll
    for (int ks = 0; ks < 2; ++ks) {
      int row = wave * 16 + a;
      int ch = (ks * 4 + h) ^ (row & 7);
      qf[ks] = *(const short8*)&lds[row * 128 + ch * 16];  // own wave's rows
    }

    f32x4 o[4] = {};
    f32x4 lacc = {};

    for (int t = 0; t <= qt; ++t) {
      const int kb = t & 1;
      if (t == qt)
        asm volatile("s_waitcnt vmcnt(0)" ::: "memory");
      else
        asm volatile("s_waitcnt vmcnt(4)" ::: "memory"); // tile t landed; t+1 in flight
      __builtin_amdgcn_s_barrier();

      const int kbase = 8192 + kb * 8192;
      const int vbase = 24576 + kb * 8192;

      // S^T = K Q^T : lane (a,h) holds S[kv = n*16+4h+r][q = qglob]
      f32x4 s[4] = {};
      __builtin_amdgcn_s_setprio(1);
      #pragma unroll
      for (int ks = 0; ks < 2; ++ks)
        #pragma unroll
        for (int n = 0; n < 4; ++n) {
          int kr = n * 16 + a;
          int ch = (ks * 4 + h) ^ (kr & 7);
          short8 kf = *(const short8*)&lds[kbase + kr * 128 + ch * 16];
          s[n] = __builtin_amdgcn_mfma_f32_16x16x32_bf16(kf, qf[ks], s[n], 0, 0, 0);
        }
      __builtin_amdgcn_s_setprio(0);

      if (t == qt) {
        #pragma unroll
        for (int n = 0; n < 4; ++n)
          #pragma unroll
          for (int r = 0; r < 4; ++r)
            if ((n * 16 + h * 4 + r) > qglob) s[n][r] = -1e30f;
      }

      // fixed-base softmax: p = exp2(s)
      #pragma unroll
      for (int n = 0; n < 4; ++n)
        #pragma unroll
        for (int r = 0; r < 4; ++r) s[n][r] = fexp2(s[n][r]);

      // P -> LDS bf16 (lane-local pack)
      #pragma unroll
      for (int n = 0; n < 4; ++n) {
        uint2 w2;
        w2.x = (unsigned)f2bf(s[n][0]) | ((unsigned)f2bf(s[n][1]) << 16);
        w2.y = (unsigned)f2bf(s[n][2]) | ((unsigned)f2bf(s[n][3]) << 16);
        *(uint2*)&lds[pbase + (a * 36 + n * 8 + h * 2) * 4] = w2;
      }

      // O += P V ; l += P 1 (ones-MFMA, register-aligned with O rows)
      __builtin_amdgcn_s_setprio(1);
      #pragma unroll
      for (int ks = 0; ks < 2; ++ks) {
        short8 pa = *(const short8*)&lds[pbase + (a * 36 + ks * 16 + h * 4) * 4];
        lacc = __builtin_amdgcn_mfma_f32_16x16x32_bf16(pa, ones, lacc, 0, 0, 0);
        #pragma unroll
        for (int n = 0; n < 4; ++n) {
          int d = n * 16 + a;
          int ch = (ks * 4 + h) ^ (d & 7);
          short8 vf = *(const short8*)&lds[vbase + d * 128 + ch * 16];
          o[n] = __builtin_amdgcn_mfma_f32_16x16x32_bf16(pa, vf, o[n], 0, 0, 0);
        }
      }
      __builtin_amdgcn_s_setprio(0);

      __builtin_amdgcn_s_barrier();        // all waves done reading buf kb
      if (t + 2 <= qt) {
        STAGE_K(kb, (t + 2) * 64);         // lands during iter t+1
        STAGE_V(kb, (t + 2) * 64);
      }
    }

    // epilogue: divide by l (register-aligned), y[b][t][head*64+d] bf16
    f32x4 inv;
    #pragma unroll
    for (int r = 0; r < 4; ++r) inv[r] = 1.0f / lacc[r];
    #pragma unroll
    for (int n = 0; n < 4; ++n)
      #pragma unroll
      for (int r = 0; r < 4; ++r) {
        int tr = q0 + wave * 16 + 4 * h + r;
        int col = hd * 64 + n * 16 + a;
        Y[((size_t)(b * Tn + tr)) * Cn + col] = f2bf(o[n][r] * inv[r]);
      }
  }
}

// ---------------------------------------------------------------------------
extern "C" void kernel_launch(void* const* d_in, const int* in_sizes, int n_in,
                              void* d_out, int out_size, void* d_ws, size_t ws_size,
                              hipStream_t stream) {
  const float* x      = (const float*)d_in[0];
  const float* W_attn = (const float*)d_in[1];
  const float* b_attn = (const float*)d_in[2];
  const float* W_proj = (const float*)d_in[3];
  const float* b_proj = (const float*)d_in[4];
  float* out = (float*)d_out;

  unsigned short* xb  = (unsigned short*)d_ws;          // [4096][1024]
  unsigned short* Wab = xb + (size_t)Mrows * Cn;        // [3072][1024]
  unsigned short* Wpb = Wab + (size_t)3 * Cn * Cn;      // [1024][1024]
  unsigned short* qkv = Wpb + (size_t)Cn * Cn;          // 3 planes of PL
  unsigned short* y   = qkv + 3 * PL;                   // [4096][1024]

  prep_all<<<4096 + 3072 + 1024, 256, 0, stream>>>(x, xb, W_attn, Wab, W_proj, Wpb);

  gemmQKV<<<256, 512, 0, stream>>>(xb, Wab, b_attn, qkv, Cn);

  // uniform blocks: each handles qt = yb and qt = 31-yb (33 iters each)
  attn_mfma<<<dim3(Bn * Hn, 16), 256, 0, stream>>>(qkv, qkv + PL, qkv + 2 * PL, y);

  gemmP<4, 2><<<dim3(Cn / 64, Mrows / 128), 256, 0, stream>>>(
      y, Wpb, b_proj, out, Cn, Cn);
}

// Round 16
// 108.474 us; speedup vs baseline: 1.0666x; 1.0010x over previous
//
#include <hip/hip_runtime.h>
#include <hip/hip_bf16.h>

static constexpr int Bn = 2, Tn = 2048, Cn = 1024, Hn = 16, HSn = 64;
static constexpr int Mrows = Bn * Tn;                 // 4096
static constexpr size_t PL = (size_t)Bn * Hn * Tn * HSn;  // one qkv plane (4.19M)

typedef __attribute__((ext_vector_type(8))) short short8;
typedef __attribute__((ext_vector_type(4))) float f32x4;

__device__ __forceinline__ unsigned short f2bf(float f) {
  __hip_bfloat16 h = __float2bfloat16(f);
  return *reinterpret_cast<unsigned short*>(&h);
}

__device__ __forceinline__ float fexp2(float x) {
  return __builtin_amdgcn_exp2f(x);
}

__device__ __forceinline__ void gload_lds16(const void* g, void* l) {
  __builtin_amdgcn_global_load_lds(
      (const __attribute__((address_space(1))) void*)g,
      (__attribute__((address_space(3))) void*)l, 16, 0, 0);
}

// qscale folded into Q plane at GEMM epilogue: (1/sqrt(64)) * log2(e)
#define QSC 0.18033688011112042591999058512524f

// ---------------------------------------------------------------------------
// merged prep kernel (unchanged)
// ---------------------------------------------------------------------------
__global__ __launch_bounds__(256) void prep_all(
    const float* __restrict__ x, unsigned short* __restrict__ xb,
    const float* __restrict__ Wa, unsigned short* __restrict__ Wab,
    const float* __restrict__ Wp, unsigned short* __restrict__ Wpb)
{
  const int bid = blockIdx.x, tid = threadIdx.x;
  if (bid < 4096) {
    int i = bid * 256 + tid;
    float4 v = ((const float4*)x)[i];
    ushort4 o;
    o.x = f2bf(v.x); o.y = f2bf(v.y); o.z = f2bf(v.z); o.w = f2bf(v.w);
    ((ushort4*)xb)[i] = o;
    return;
  }
  __shared__ float tile[32][33];
  const float* src; unsigned short* dst; int R, Cc, tb;
  if (bid < 4096 + 3072) { src = Wa; dst = Wab; R = Cn; Cc = 3 * Cn; tb = bid - 4096; }
  else                   { src = Wp; dst = Wpb; R = Cn; Cc = Cn;     tb = bid - 4096 - 3072; }
  const int nbx = Cc / 32;
  const int bx = tb % nbx, by = tb / nbx;
  const int tx = tid & 31, ty = tid >> 5;
  const int c0 = bx * 32, r0 = by * 32;
  #pragma unroll
  for (int i = 0; i < 4; ++i)
    tile[ty + 8 * i][tx] = src[(size_t)(r0 + ty + 8 * i) * Cc + c0 + tx];
  __syncthreads();
  #pragma unroll
  for (int i = 0; i < 4; ++i)
    dst[(size_t)(c0 + ty + 8 * i) * R + r0 + tx] = f2bf(tile[tx][ty + 8 * i]);
}

// ---------------------------------------------------------------------------
// QKV GEMM v2: 256x192 tile, grid 256 (1/CU), XCD swizzle, 8 waves (2Mx4N).
// BK=32, FOUR LDS buffers (4x28KB), depth-3 prefetch, counted vmcnt,
// ONE barrier per K-step, NO lgkmcnt drain: STAGE(t+3) targets buf[(t-1)&3],
// which is dead (all step t-1 ds_reads were consumed by MFMAs issued before
// barrier t; lgkm completes in order). Reads and MFMA interleave freely.
// Waves 0-3 stage the 16 A frags (4 each, vmcnt 8/4/0); waves 4-7 stage the
// 12 B frags (3 each, vmcnt 6/3/0) — wave-uniform branches.
// ---------------------------------------------------------------------------
__global__ __launch_bounds__(512) void gemmQKV(
    const unsigned short* __restrict__ A, const unsigned short* __restrict__ Bt,
    const float* __restrict__ bias, unsigned short* __restrict__ qkv, int K)
{
  constexpr int NSTEP = 32;            // K=1024 / BK=32
  constexpr int AF = 16;               // A frags per buffer (16 rows x 32k each)
  constexpr int BF = 12;               // B frags per buffer
  constexpr int FB = (AF + BF) * 1024; // 28672 B per buffer
  __shared__ alignas(16) unsigned char lds[4][FB];   // 112 KB

  const int tid = threadIdx.x, wave = tid >> 6, lane = tid & 63;
  const int wr = wave >> 2, wc = wave & 3;            // 2 x 4 wave grid
  const int orig = blockIdx.x;
  const int swz = (orig & 7) * 32 + (orig >> 3);      // XCD swizzle
  const int bx = swz & 15, by = swz >> 4;
  const int tM = by * 256, tN = bx * 192;

  auto STAGE = [&](int buf, int k0) {
    if (wave < 4) {
      #pragma unroll
      for (int i = 0; i < 4; ++i) {
        int f = wave * 4 + i;                         // A frag 0..15
        const unsigned short* g =
            A + (size_t)(tM + f * 16 + (lane & 15)) * K + k0 + (lane >> 4) * 8;
        gload_lds16(g, &lds[buf][f * 1024]);
      }
    } else {
      #pragma unroll
      for (int i = 0; i < 3; ++i) {
        int fg = (wave - 4) * 3 + i;                  // B frag 0..11
        const unsigned short* g =
            Bt + (size_t)(tN + fg * 16 + (lane & 15)) * K + k0 + (lane >> 4) * 8;
        gload_lds16(g, &lds[buf][AF * 1024 + fg * 1024]);
      }
    }
  };

  f32x4 acc[8][3] = {};

  STAGE(0, 0);
  STAGE(1, 32);
  STAGE(2, 64);

  for (int t = 0; t < NSTEP; ++t) {
    const int ahead = NSTEP - 1 - t;
    if (wave < 4) {
      if (ahead >= 2)      asm volatile("s_waitcnt vmcnt(8)" ::: "memory");
      else if (ahead == 1) asm volatile("s_waitcnt vmcnt(4)" ::: "memory");
      else                 asm volatile("s_waitcnt vmcnt(0)" ::: "memory");
    } else {
      if (ahead >= 2)      asm volatile("s_waitcnt vmcnt(6)" ::: "memory");
      else if (ahead == 1) asm volatile("s_waitcnt vmcnt(3)" ::: "memory");
      else                 asm volatile("s_waitcnt vmcnt(0)" ::: "memory");
    }
    __builtin_amdgcn_s_barrier();

    if (t + 3 < NSTEP) STAGE((t + 3) & 3, (t + 3) * 32);

    const unsigned char* base = lds[t & 3];
    short8 af[8], bfr[3];
    #pragma unroll
    for (int m = 0; m < 8; ++m)
      af[m] = *(const short8*)&base[(wr * 8 + m) * 1024 + lane * 16];
    #pragma unroll
    for (int n = 0; n < 3; ++n)
      bfr[n] = *(const short8*)&base[AF * 1024 + (wc * 3 + n) * 1024 + lane * 16];
    #pragma unroll
    for (int m = 0; m < 8; ++m)
      #pragma unroll
      for (int n = 0; n < 3; ++n)
        acc[m][n] = __builtin_amdgcn_mfma_f32_16x16x32_bf16(af[m], bfr[n], acc[m][n], 0, 0, 0);
  }

  // epilogue (unchanged): bias, Q*QSC, Q/K head-major bf16, V^T bf16
  const int a = lane & 15, hq = lane >> 4;
  #pragma unroll
  for (int m = 0; m < 8; ++m) {
    #pragma unroll
    for (int n = 0; n < 3; ++n) {
      int c = tN + wc * 48 + n * 16 + a;
      float bv = bias[c];
      int which = c >> 10;
      int cc = c & 1023, hh = cc >> 6, d = cc & 63;
      int row0 = tM + wr * 128 + m * 16 + hq * 4;
      int b = row0 >> 11, t0 = row0 & 2047;
      int bh = b * Hn + hh;
      if (which == 2) {
        ushort4 pk;
        pk.x = f2bf(acc[m][n][0] + bv);
        pk.y = f2bf(acc[m][n][1] + bv);
        pk.z = f2bf(acc[m][n][2] + bv);
        pk.w = f2bf(acc[m][n][3] + bv);
        *(ushort4*)&qkv[2 * PL + ((size_t)bh * HSn + d) * Tn + t0] = pk;
      } else {
        float sc = (which == 0) ? QSC : 1.0f;
        #pragma unroll
        for (int r = 0; r < 4; ++r) {
          float v = (acc[m][n][r] + bv) * sc;
          qkv[(size_t)which * PL + ((size_t)bh * Tn + t0 + r) * HSn + d] = f2bf(v);
        }
      }
    }
  }
}

// ---------------------------------------------------------------------------
// proj GEMM (unchanged R7 structure)
// ---------------------------------------------------------------------------
template <int WM, int WN>
__global__ __launch_bounds__(256) void gemmP(
    const unsigned short* __restrict__ A, const unsigned short* __restrict__ Bt,
    const float* __restrict__ bias, float* __restrict__ O, int N, int K)
{
  constexpr int BM = WM * 32, BNt = WN * 32;
  constexpr int AF = BM / 16;
  constexpr int BF = BNt / 16;
  constexpr int NF = AF + BF;
  constexpr int PW = NF / 4;
  static_assert(PW == 3, "vmcnt literal");
  __shared__ alignas(16) unsigned char lds[2][NF * 1024];

  const int tid = threadIdx.x, wave = tid >> 6, lane = tid & 63;
  const int wr = wave >> 1, wc = wave & 1;
  const int tM = blockIdx.y * BM, tN = blockIdx.x * BNt;

  auto STAGE = [&](int buf, int k0) {
    #pragma unroll
    for (int i = 0; i < PW; ++i) {
      int f = wave * PW + i;
      const unsigned short* g;
      if (f < AF)
        g = A + (size_t)(tM + f * 16 + (lane & 15)) * K + k0 + (lane >> 4) * 8;
      else
        g = Bt + (size_t)(tN + (f - AF) * 16 + (lane & 15)) * K + k0 + (lane >> 4) * 8;
      gload_lds16(g, &lds[buf][f * 1024]);
    }
  };

  f32x4 acc[WM][WN] = {};

  STAGE(0, 0);
  for (int t = 0, k0 = 0;; ++t, k0 += 32) {
    const int cur = t & 1;
    if (k0 + 32 < K) {
      STAGE(cur ^ 1, k0 + 32);
      asm volatile("s_waitcnt vmcnt(3)" ::: "memory");
    } else {
      asm volatile("s_waitcnt vmcnt(0)" ::: "memory");
    }
    __builtin_amdgcn_s_barrier();

    short8 af[WM], bfr[WN];
    #pragma unroll
    for (int m = 0; m < WM; ++m)
      af[m] = *(const short8*)&lds[cur][(wr * WM + m) * 1024 + lane * 16];
    #pragma unroll
    for (int n = 0; n < WN; ++n)
      bfr[n] = *(const short8*)&lds[cur][(AF + wc * WN + n) * 1024 + lane * 16];
    #pragma unroll
    for (int m = 0; m < WM; ++m)
      #pragma unroll
      for (int n = 0; n < WN; ++n)
        acc[m][n] = __builtin_amdgcn_mfma_f32_16x16x32_bf16(af[m], bfr[n], acc[m][n], 0, 0, 0);

    __builtin_amdgcn_s_barrier();
    if (k0 + 32 >= K) break;
  }

  const int a = lane & 15, hq = lane >> 4;
  #pragma unroll
  for (int m = 0; m < WM; ++m) {
    #pragma unroll
    for (int n = 0; n < WN; ++n) {
      int c = tN + wc * (WN * 16) + n * 16 + a;
      float bv = bias[c];
      int r0 = tM + wr * (WM * 16) + m * 16 + hq * 4;
      #pragma unroll
      for (int r = 0; r < 4; ++r)
        O[(size_t)(r0 + r) * N + c] = acc[m][n][r] + bv;
    }
  }
}

// ---------------------------------------------------------------------------
// Flash attention v4 (unchanged from R15: uniform paired blocks, pipeline,
// fixed-base softmax, ones-MFMA l)
// ---------------------------------------------------------------------------
__global__ __launch_bounds__(256) void attn_mfma(
    const unsigned short* __restrict__ Qg, const unsigned short* __restrict__ Kg,
    const unsigned short* __restrict__ Vtg, unsigned short* __restrict__ Y)
{
  __shared__ alignas(16) unsigned char lds[50176];
  const int bh = blockIdx.x;
  const int yb = blockIdx.y;                            // 0..15
  const int tid = threadIdx.x, wave = tid >> 6, lane = tid & 63;
  const int a = lane & 15, h = lane >> 4;
  const unsigned short* Qp = Qg + (size_t)bh * Tn * HSn;
  const unsigned short* Kp = Kg + (size_t)bh * Tn * HSn;
  const unsigned short* Vp = Vtg + (size_t)bh * HSn * Tn;   // [64][2048]
  const int pbase = 40960 + wave * 2304;
  const int qglob = wave * 16 + a;
  const int b = bh >> 4, hd = bh & 15;

  auto STAGE_K = [&](int kb, int kv0) {
    #pragma unroll
    for (int i = 0; i < 2; ++i) {
      int r8 = wave * 16 + i * 8;
      int row = r8 + (lane >> 3);
      int ch = (lane & 7) ^ (row & 7);
      gload_lds16(Kp + (size_t)(kv0 + row) * HSn + ch * 8,
                  &lds[8192 + kb * 8192 + r8 * 128]);
    }
  };
  auto STAGE_V = [&](int vb, int kv0) {
    #pragma unroll
    for (int i = 0; i < 2; ++i) {
      int r8 = wave * 16 + i * 8;
      int row = r8 + (lane >> 3);
      int ch = (lane & 7) ^ (row & 7);
      gload_lds16(Vp + (size_t)row * Tn + kv0 + ch * 8,
                  &lds[24576 + vb * 8192 + r8 * 128]);
    }
  };

  short8 ones;
  #pragma unroll
  for (int j = 0; j < 8; ++j) ones[j] = (short)0x3F80;    // bf16 1.0

  for (int ph = 0; ph < 2; ++ph) {
    const int qt = ph ? (31 - yb) : yb;
    const int q0 = qt * 64;

    #pragma unroll
    for (int i = 0; i < 2; ++i) {
      int r8 = wave * 16 + i * 8;
      int row = r8 + (lane >> 3);
      int ch = (lane & 7) ^ (row & 7);
      gload_lds16(Qp + (size_t)(q0 + row) * HSn + ch * 8, &lds[r8 * 128]);
    }
    STAGE_K(0, 0);
    STAGE_V(0, 0);
    if (qt >= 1) {
      STAGE_K(1, 64);
      STAGE_V(1, 64);
      asm volatile("s_waitcnt vmcnt(8)" ::: "memory");   // Q landed
    } else {
      asm volatile("s_waitcnt vmcnt(4)" ::: "memory");   // Q landed
    }

    short8 qf[2];
    #pragma unroll
    for (int ks = 0; ks < 2; ++ks) {
      int row = wave * 16 + a;
      int ch = (ks * 4 + h) ^ (row & 7);
      qf[ks] = *(const short8*)&lds[row * 128 + ch * 16];  // own wave's rows
    }

    f32x4 o[4] = {};
    f32x4 lacc = {};

    for (int t = 0; t <= qt; ++t) {
      const int kb = t & 1;
      if (t == qt)
        asm volatile("s_waitcnt vmcnt(0)" ::: "memory");
      else
        asm volatile("s_waitcnt vmcnt(4)" ::: "memory"); // tile t landed; t+1 in flight
      __builtin_amdgcn_s_barrier();

      const int kbase = 8192 + kb * 8192;
      const int vbase = 24576 + kb * 8192;

      f32x4 s[4] = {};
      __builtin_amdgcn_s_setprio(1);
      #pragma unroll
      for (int ks = 0; ks < 2; ++ks)
        #pragma unroll
        for (int n = 0; n < 4; ++n) {
          int kr = n * 16 + a;
          int ch = (ks * 4 + h) ^ (kr & 7);
          short8 kf = *(const short8*)&lds[kbase + kr * 128 + ch * 16];
          s[n] = __builtin_amdgcn_mfma_f32_16x16x32_bf16(kf, qf[ks], s[n], 0, 0, 0);
        }
      __builtin_amdgcn_s_setprio(0);

      if (t == qt) {
        #pragma unroll
        for (int n = 0; n < 4; ++n)
          #pragma unroll
          for (int r = 0; r < 4; ++r)
            if ((n * 16 + h * 4 + r) > qglob) s[n][r] = -1e30f;
      }

      #pragma unroll
      for (int n = 0; n < 4; ++n)
        #pragma unroll
        for (int r = 0; r < 4; ++r) s[n][r] = fexp2(s[n][r]);

      #pragma unroll
      for (int n = 0; n < 4; ++n) {
        uint2 w2;
        w2.x = (unsigned)f2bf(s[n][0]) | ((unsigned)f2bf(s[n][1]) << 16);
        w2.y = (unsigned)f2bf(s[n][2]) | ((unsigned)f2bf(s[n][3]) << 16);
        *(uint2*)&lds[pbase + (a * 36 + n * 8 + h * 2) * 4] = w2;
      }

      __builtin_amdgcn_s_setprio(1);
      #pragma unroll
      for (int ks = 0; ks < 2; ++ks) {
        short8 pa = *(const short8*)&lds[pbase + (a * 36 + ks * 16 + h * 4) * 4];
        lacc = __builtin_amdgcn_mfma_f32_16x16x32_bf16(pa, ones, lacc, 0, 0, 0);
        #pragma unroll
        for (int n = 0; n < 4; ++n) {
          int d = n * 16 + a;
          int ch = (ks * 4 + h) ^ (d & 7);
          short8 vf = *(const short8*)&lds[vbase + d * 128 + ch * 16];
          o[n] = __builtin_amdgcn_mfma_f32_16x16x32_bf16(pa, vf, o[n], 0, 0, 0);
        }
      }
      __builtin_amdgcn_s_setprio(0);

      __builtin_amdgcn_s_barrier();        // all waves done reading buf kb
      if (t + 2 <= qt) {
        STAGE_K(kb, (t + 2) * 64);         // lands during iter t+1
        STAGE_V(kb, (t + 2) * 64);
      }
    }

    f32x4 inv;
    #pragma unroll
    for (int r = 0; r < 4; ++r) inv[r] = 1.0f / lacc[r];
    #pragma unroll
    for (int n = 0; n < 4; ++n)
      #pragma unroll
      for (int r = 0; r < 4; ++r) {
        int tr = q0 + wave * 16 + 4 * h + r;
        int col = hd * 64 + n * 16 + a;
        Y[((size_t)(b * Tn + tr)) * Cn + col] = f2bf(o[n][r] * inv[r]);
      }
  }
}

// ---------------------------------------------------------------------------
extern "C" void kernel_launch(void* const* d_in, const int* in_sizes, int n_in,
                              void* d_out, int out_size, void* d_ws, size_t ws_size,
                              hipStream_t stream) {
  const float* x      = (const float*)d_in[0];
  const float* W_attn = (const float*)d_in[1];
  const float* b_attn = (const float*)d_in[2];
  const float* W_proj = (const float*)d_in[3];
  const float* b_proj = (const float*)d_in[4];
  float* out = (float*)d_out;

  unsigned short* xb  = (unsigned short*)d_ws;          // [4096][1024]
  unsigned short* Wab = xb + (size_t)Mrows * Cn;        // [3072][1024]
  unsigned short* Wpb = Wab + (size_t)3 * Cn * Cn;      // [1024][1024]
  unsigned short* qkv = Wpb + (size_t)Cn * Cn;          // 3 planes of PL
  unsigned short* y   = qkv + 3 * PL;                   // [4096][1024]

  prep_all<<<4096 + 3072 + 1024, 256, 0, stream>>>(x, xb, W_attn, Wab, W_proj, Wpb);

  gemmQKV<<<256, 512, 0, stream>>>(xb, Wab, b_attn, qkv, Cn);

  attn_mfma<<<dim3(Bn * Hn, 16), 256, 0, stream>>>(qkv, qkv + PL, qkv + 2 * PL, y);

  gemmP<4, 2><<<dim3(Cn / 64, Mrows / 128), 256, 0, stream>>>(
      y, Wpb, b_proj, out, Cn, Cn);
}